// Round 3
// baseline (264.303 us; speedup 1.0000x reference)
//
#include <hip/hip_runtime.h>
#include <cstddef>

// Problem constants
#define B_TOT   256
#define IN_CAPS 1152
#define KDIM    8
#define NJ      10
#define ND      16
#define JD      160                 // NJ*ND

// Tiling
#define BB      8                   // batches per block (register reuse of W)
#define ISPLIT  24                  // i-splits -> grid = (256/8)*24 = 768 blocks (3/CU)
#define IRANGE  (IN_CAPS/ISPLIT)    // 48
#define CI      8                   // i's per chunk (= i_par groups)
#define NCHUNK  (IRANGE/CI)         // 6
#define NTHREADS 320                // 8 i_par * 10 j * 4 dq = 5 waves
#define GRID    ((B_TOT/BB)*ISPLIT) // 768
#define WCHUNK_F4 (CI*KDIM*4*NJ)    // 2560 float4 = 40960 B

__device__ __forceinline__ float dot4(float4 a, float4 b) {
    return a.x*b.x + a.y*b.y + a.z*b.z + a.w*b.w;
}
__device__ __forceinline__ float getc(const float4& v, int k) {
    switch (k) { case 0: return v.x; case 1: return v.y; case 2: return v.z; default: return v.w; }
}

// One routing iteration. W is staged per-chunk into LDS with fully-coalesced
// global loads (1KB/wave-instr) into a permuted [i][k][dq][j] layout (bank-
// balanced for both the staging write and the (j,dq)-lane compute read).
// Each ds_read_b128 of W feeds 8 batches (BB=8) -> 32 FMAs per LDS read.
// x is read from global per chunk (wave-broadcast within i_par groups, L1-hot).
// !FIRST: c = softmax_j(u_hat . vsum); logits in registers via dq-quad shuffle,
// denominator through a tiny LDS tile.
template<bool FIRST, bool PARTIAL>
__global__ __launch_bounds__(NTHREADS, 3)
void iter_kernel(const float* __restrict__ x, const float* __restrict__ Wt,
                 const float* __restrict__ vsum, float* __restrict__ s_out)
{
    const int isp = blockIdx.x % ISPLIT;   // isp % 8 == XCD id -> 3 W slices/XCD, L2-resident
    const int g   = blockIdx.x / ISPLIT;
    const int b0  = g * BB;
    const int i_begin = isp * IRANGE;

    const int t = threadIdx.x;
    const int i_par = t / 40;              // 0..7
    const int r  = t - i_par * 40;
    const int j  = r >> 2;                 // 0..9
    const int dq = r & 3;                  // 0..3 (owns d = dq*4..dq*4+3)

    __shared__ float4 w_lds[WCHUNK_F4];        // 40960 B, reused as reduction buf
    __shared__ float  logit_lds[BB][CI][NJ];   // 2560 B
    __shared__ float  denom_lds[BB][CI];       // 256 B (reciprocal)

    float4 vs[BB];
    if (!FIRST) {
        #pragma unroll
        for (int bb = 0; bb < BB; ++bb)
            vs[bb] = *(const float4*)(vsum + (size_t)(b0 + bb) * JD + j * ND + dq * 4);
    }

    float4 s_acc[BB];
    #pragma unroll
    for (int bb = 0; bb < BB; ++bb) s_acc[bb] = make_float4(0.f, 0.f, 0.f, 0.f);

    const float4* Wf4 = (const float4*)Wt;

    for (int c = 0; c < NCHUNK; ++c) {
        __syncthreads();   // (A) prev chunk's LDS reads complete
        // ---- stage W chunk: 2560 float4, contiguous global, permuted LDS ----
        const size_t base_f4 = (size_t)(i_begin + c * CI) * (NJ * KDIM * 4);
        #pragma unroll
        for (int s = 0; s < WCHUNK_F4 / NTHREADS; ++s) {   // 8 iters
            const int f = t + s * NTHREADS;
            float4 v = Wf4[base_f4 + f];                   // fully coalesced
            const int dq_  = f & 3;
            const int k_   = (f >> 2) & 7;
            const int rest = f >> 5;                       // j + 10*i_loc
            const int j_   = rest % 10;
            const int il_  = rest / 10;
            w_lds[((il_ * KDIM + k_) * 4 + dq_) * NJ + j_] = v;
        }
        __syncthreads();   // (B) staging visible

        // ---- compute u_hat for this thread's i, 8 batches ----
        const int i_glob = i_begin + c * CI + i_par;
        float4 u[BB];
        #pragma unroll
        for (int bb = 0; bb < BB; ++bb) u[bb] = make_float4(0.f, 0.f, 0.f, 0.f);

        #pragma unroll
        for (int kk = 0; kk < 2; ++kk) {
            float4 xk[BB];
            #pragma unroll
            for (int bb = 0; bb < BB; ++bb)
                xk[bb] = ((const float4*)(x + ((size_t)(b0 + bb) * IN_CAPS + i_glob) * KDIM))[kk];
            #pragma unroll
            for (int k4 = 0; k4 < 4; ++k4) {
                float4 w4 = w_lds[((i_par * KDIM + kk * 4 + k4) * 4 + dq) * NJ + j];
                #pragma unroll
                for (int bb = 0; bb < BB; ++bb) {
                    const float xs = getc(xk[bb], k4);
                    u[bb].x += xs * w4.x; u[bb].y += xs * w4.y;
                    u[bb].z += xs * w4.z; u[bb].w += xs * w4.w;
                }
            }
        }

        if (FIRST) {
            #pragma unroll
            for (int bb = 0; bb < BB; ++bb) {
                s_acc[bb].x += u[bb].x; s_acc[bb].y += u[bb].y;
                s_acc[bb].z += u[bb].z; s_acc[bb].w += u[bb].w;
            }
        } else {
            float lg[BB];
            #pragma unroll
            for (int bb = 0; bb < BB; ++bb) {
                float l = dot4(u[bb], vs[bb]);
                l += __shfl_xor(l, 1);       // sum over the 4-lane d-quad
                l += __shfl_xor(l, 2);
                lg[bb] = l;
                if (dq == 0) logit_lds[bb][i_par][j] = l;
            }
            __syncthreads();   // (C)
            if (t < BB * CI) {                // 64 threads: softmax denominators
                const int bb = t >> 3, il = t & 7;
                float den = 0.f;
                #pragma unroll
                for (int q = 0; q < NJ; ++q) den += __expf(logit_lds[bb][il][q]);
                denom_lds[bb][il] = 1.0f / den;   // |logit| small: no max-shift
            }
            __syncthreads();   // (D)
            #pragma unroll
            for (int bb = 0; bb < BB; ++bb) {
                const float cc = __expf(lg[bb]) * denom_lds[bb][i_par];
                s_acc[bb].x += cc * u[bb].x; s_acc[bb].y += cc * u[bb].y;
                s_acc[bb].z += cc * u[bb].z; s_acc[bb].w += cc * u[bb].w;
            }
        }
    }

    // ---- block reduction over the 8 i_par groups; reuse w_lds as scratch ----
    __syncthreads();                          // last chunk's w_lds reads done
    float* red = (float*)w_lds;               // [8][BB*JD] = 40960 B, exact fit
    #pragma unroll
    for (int bb = 0; bb < BB; ++bb)
        ((float4*)red)[i_par * (BB * JD / 4) + bb * (JD / 4) + j * 4 + dq] = s_acc[bb];
    __syncthreads();
    const float premul = FIRST ? 0.1f : 1.0f; // softmax(zeros) over 10 caps = 0.1
    for (int e = t; e < BB * JD; e += NTHREADS) {   // 4 per thread, coalesced
        float v = 0.f;
        #pragma unroll
        for (int ip = 0; ip < CI; ++ip) v += red[ip * (BB * JD) + e];
        v *= premul;
        const int bb = e / JD, jd = e - bb * JD;
        if (PARTIAL)
            s_out[((size_t)isp * B_TOT + b0 + bb) * JD + jd] = v;  // unique owner
        else
            unsafeAtomicAdd(&s_out[(size_t)(b0 + bb) * JD + jd], v);
    }
}

// squash per (b,j): v = s * s2/(1+s2)/sqrt(s2+eps); 16-lane shuffle reduction.
// P partial slices summed first. mode 0: vsum = v; 1: vsum += v; 2: out = v.
template<int P>
__global__ __launch_bounds__(256)
void squash_kernel(float* __restrict__ s, float* __restrict__ vsum,
                   float* __restrict__ out, int mode)
{
    int idx = blockIdx.x * 256 + threadIdx.x;    // grid 160 -> 40960
    float sv = 0.f;
    #pragma unroll
    for (int p = 0; p < P; ++p) sv += s[(size_t)p * B_TOT * JD + idx];
    if (P == 1) s[idx] = 0.f;                    // atomic path: re-zero accumulator
    float sq = sv * sv;
    sq += __shfl_xor(sq, 1);
    sq += __shfl_xor(sq, 2);
    sq += __shfl_xor(sq, 4);
    sq += __shfl_xor(sq, 8);                     // sum over 16 d-lanes (16-aligned)
    float scale = sq / (1.0f + sq) / sqrtf(sq + 1e-7f);
    float v = sv * scale;
    if (mode == 0)      vsum[idx] = v;
    else if (mode == 1) vsum[idx] += v;
    else                out[idx] = v;
}

extern "C" void kernel_launch(void* const* d_in, const int* in_sizes, int n_in,
                              void* d_out, int out_size, void* d_ws, size_t ws_size,
                              hipStream_t stream)
{
    const float* x  = (const float*)d_in[0];   // [256,1152,8]
    const float* Wt = (const float*)d_in[1];   // [1152,10,8,16]
    float* out = (float*)d_out;                // [256,10,16]

    dim3 grid(GRID), blk(NTHREADS);
    dim3 sgrid((B_TOT * JD) / 256), sblk(256);

    const size_t slice = (size_t)B_TOT * JD;                    // 40960 floats
    const size_t need  = (ISPLIT + 1) * slice * sizeof(float);  // 4.1 MB

    if (ws_size >= need) {
        // partial-slice path: no global atomics, no memset, deterministic
        float* s_part = (float*)d_ws;              // [24][256][160]
        float* vsum   = s_part + (size_t)ISPLIT * slice;

        iter_kernel<true,  true><<<grid, blk, 0, stream>>>(x, Wt, nullptr, s_part);
        squash_kernel<ISPLIT><<<sgrid, sblk, 0, stream>>>(s_part, vsum, out, 0); // vsum = v1
        iter_kernel<false, true><<<grid, blk, 0, stream>>>(x, Wt, vsum, s_part);
        squash_kernel<ISPLIT><<<sgrid, sblk, 0, stream>>>(s_part, vsum, out, 1); // vsum = v1+v2
        iter_kernel<false, true><<<grid, blk, 0, stream>>>(x, Wt, vsum, s_part);
        squash_kernel<ISPLIT><<<sgrid, sblk, 0, stream>>>(s_part, vsum, out, 2); // out = v3
    } else {
        // fallback: single accumulator slice + global atomics
        float* s    = (float*)d_ws;
        float* vsum = s + slice;
        hipMemsetAsync(d_ws, 0, slice * sizeof(float), stream);

        iter_kernel<true,  false><<<grid, blk, 0, stream>>>(x, Wt, nullptr, s);
        squash_kernel<1><<<sgrid, sblk, 0, stream>>>(s, vsum, out, 0);
        iter_kernel<false, false><<<grid, blk, 0, stream>>>(x, Wt, vsum, s);
        squash_kernel<1><<<sgrid, sblk, 0, stream>>>(s, vsum, out, 1);
        iter_kernel<false, false><<<grid, blk, 0, stream>>>(x, Wt, vsum, s);
        squash_kernel<1><<<sgrid, sblk, 0, stream>>>(s, vsum, out, 2);
    }
}